// Round 9
// baseline (132.064 us; speedup 1.0000x reference)
//
#include <hip/hip_runtime.h>

typedef __bf16 bf16x8 __attribute__((ext_vector_type(8)));
typedef float f32x4 __attribute__((ext_vector_type(4)));
typedef unsigned int u32x4 __attribute__((ext_vector_type(4)));

#define T_SEQ 8192
#define NB 2
#define CDIM 1024
#define HDIM 64
#define NROWS (NB * T_SEQ)  // 16384

static __device__ __forceinline__ unsigned short f2b(float f) {
    unsigned u = __float_as_uint(f);
    return (unsigned short)((u + 0x7FFFu + ((u >> 16) & 1u)) >> 16);
}

static __device__ __forceinline__ unsigned bpack(float lo, float hi) {
    unsigned a = __float_as_uint(lo), b = __float_as_uint(hi);
    a = (a + 0x7FFFu + ((a >> 16) & 1u)) >> 16;   // RNE f32->bf16
    b = (b + 0x7FFFu + ((b >> 16) & 1u)) >> 16;
    return a | (b << 16);
}

// async 16B global->LDS.  LDS dest must be wave-uniform (lane*16 auto-added).
static __device__ __forceinline__ void gll16(const void* g, void* l) {
    __builtin_amdgcn_global_load_lds(
        (const __attribute__((address_space(1))) unsigned int*)(unsigned long long)g,
        (__attribute__((address_space(3))) unsigned int*)(unsigned long long)l,
        16, 0, 0);
}

// ---------------------------------------------------------------------------
// Kernel 1: WT[m][n][k] = W_m[k][n] as bf16 bits.  m in {0=q,1=k,2=v}.
// ---------------------------------------------------------------------------
__global__ __launch_bounds__(256) void wt_kernel(const float* __restrict__ Wq,
                                                 const float* __restrict__ Wk,
                                                 const float* __restrict__ Wv,
                                                 unsigned short* __restrict__ WT) {
    int idx = blockIdx.x * 256 + threadIdx.x;  // < 3*64*1024
    int m   = idx >> 16;
    int rem = idx & 65535;
    int n = rem >> 10, k = rem & 1023;
    const float* W = (m == 0) ? Wq : (m == 1) ? Wk : Wv;
    WT[idx] = f2b(W[k * HDIM + n]);
}

// ---------------------------------------------------------------------------
// Kernel 2: QKV projection, m97 structure, 8-wave blocks (512 thr).
// BM=32, BN=192, BK=64, 16 K-steps.  Wave w: rowgroup rg=w&1 (16 rows),
// colgroup cgp=w>>1 (48 cols), acc[1][3] -> 6 MFMA/step/wave.
// global_load_lds staging (4 gll/thread: 1 A + 3 B), double buffered, one
// barrier/step.  16B-slot XOR swizzle on BOTH tiles (rule #21): linear LDS
// dest, inverse-swizzled global source, swizzled ds_read -> all 32 banks.
// 512 blocks x 8 waves, 64 KB LDS -> 2 blocks/CU = 16 waves/CU = 4/SIMD.
// ---------------------------------------------------------------------------
__global__ __launch_bounds__(512) void qkv_kernel(const float* __restrict__ x,
                                                  const unsigned short* __restrict__ WT,
                                                  float* __restrict__ q,
                                                  float* __restrict__ k,
                                                  float* __restrict__ v) {
    __shared__ float          Af[2][32 * 64];    // 8 KB each:  row = 16 slots of 16B (4 f32)
    __shared__ unsigned short Bf[2][192 * 64];   // 24 KB each: row = 8 slots of 16B (8 bf16)

    const int tid  = threadIdx.x;                // 0..511
    const int lane = tid & 63;
    const int w    = tid >> 6;                   // 0..7
    const int rg   = w & 1;                      // row group (16 rows)
    const int cgp  = w >> 1;                     // col group (48 cols)
    const int lr   = lane & 15, lg = lane >> 4;
    const long row0 = (long)blockIdx.x * 32;

    // ---- A staging: thread covers LDS 16B slot at byte L = tid*16 ----
    //      row r = tid>>4, phys slot p = tid&15; source slot = p ^ (r&15).
    const int ar  = tid >> 4;
    const int ap  = tid & 15;
    const float* asrc = x + (row0 + ar) * CDIM + ((ap ^ (ar & 15)) << 2);

    // ---- B staging: L = tid*16 + i*8192 (i=0..2); row r=L>>7, phys p=(L>>4)&7;
    //      source ushort offset = (p ^ (r&7))*8.
    const unsigned short* bsrc[3];
    #pragma unroll
    for (int i = 0; i < 3; ++i) {
        int L = tid * 16 + i * 8192;
        int r = L >> 7;
        int p = (L >> 4) & 7;
        bsrc[i] = WT + r * CDIM + ((p ^ (r & 7)) << 3);
    }
    const int wlds = w << 10;   // wave-uniform LDS byte base offset (lane*16 auto)

    f32x4 acc[3];
    #pragma unroll
    for (int ni = 0; ni < 3; ++ni) acc[ni] = (f32x4){0.f, 0.f, 0.f, 0.f};

    #define STAGE(buf, kt)                                                        \
        do {                                                                      \
            gll16(asrc + (kt), (char*)&Af[buf][0] + wlds);                        \
            _Pragma("unroll")                                                     \
            for (int i = 0; i < 3; ++i)                                           \
                gll16(bsrc[i] + (kt), (char*)&Bf[buf][0] + wlds + i * 8192);      \
        } while (0)

    STAGE(0, 0);
    __syncthreads();   // compiler drains vmcnt(0) before s_barrier

    const int arow = rg * 16 + lr;        // A row this lane consumes
    const int amsk = lr & 15;             // A slot swizzle mask
    for (int t = 0; t < 16; ++t) {
        const int cur = t & 1;
        if (t < 15) STAGE(cur ^ 1, (t + 1) * 64);

        const float*          Ab = Af[cur];
        const unsigned short* Bb = Bf[cur];
        #pragma unroll
        for (int ks = 0; ks < 2; ++ks) {
            // logical 16B slots s0,s0+1 hold floats ks*32+lg*8 .. +7
            const int s0 = ks * 8 + lg * 2;
            f32x4 l0 = *(const f32x4*)&Ab[arow * 64 + ((s0 ^ amsk) << 2)];
            f32x4 h0 = *(const f32x4*)&Ab[arow * 64 + (((s0 + 1) ^ amsk) << 2)];
            u32x4 p0;
            p0.x = bpack(l0[0], l0[1]); p0.y = bpack(l0[2], l0[3]);
            p0.z = bpack(h0[0], h0[1]); p0.w = bpack(h0[2], h0[3]);
            bf16x8 a0 = __builtin_bit_cast(bf16x8, p0);
            #pragma unroll
            for (int ni = 0; ni < 3; ++ni) {
                int brow = cgp * 48 + ni * 16 + lr;
                int bpos = ((ks * 4 + lg) ^ (brow & 7)) << 3;  // ushort offset
                u32x4 bu = *(const u32x4*)&Bb[brow * 64 + bpos];
                bf16x8 bfv = __builtin_bit_cast(bf16x8, bu);
                acc[ni] = __builtin_amdgcn_mfma_f32_16x16x32_bf16(a0, bfv, acc[ni], 0, 0, 0);
            }
        }
        __syncthreads();
    }
    #undef STAGE

    // ---- epilogue: C/D layout col=lane&15, row=(lane>>4)*4+j ----
    #pragma unroll
    for (int ni = 0; ni < 3; ++ni) {
        int g   = cgp * 48 + ni * 16 + lr;   // 0..191
        int mat = g >> 6, cc = g & 63;
        float* op = (mat == 0) ? q : (mat == 1) ? k : v;
        long rbase = row0 + rg * 16 + lg * 4;
        #pragma unroll
        for (int j = 0; j < 4; ++j)
            op[(rbase + j) * HDIM + cc] = acc[ni][j];
    }
}

// ---------------------------------------------------------------------------
// Kernel 3: local-window attention.  Thread = (row, octet p: 8 dims).
// 256 thr = 32 rows/block; grid (256, 2).  Linear block id keeps attn blocks
// on the XCD whose L2 holds their q/k/v.
// ---------------------------------------------------------------------------
#define DOT4(a, b) ((a).x*(b).x + (a).y*(b).y + (a).z*(b).z + (a).w*(b).w)

__global__ __launch_bounds__(256) void attn_kernel(const float* __restrict__ q,
                                                   const float* __restrict__ k,
                                                   const float* __restrict__ v,
                                                   float* __restrict__ out) {
    int tid = threadIdx.x;
    int b   = blockIdx.y;
    int r   = tid >> 3, p = tid & 7;
    int il  = blockIdx.x * 32 + r;               // row within batch

    const float* qp = q + ((long)b * T_SEQ + il) * HDIM + p * 8;
    const float* kb = k + (long)b * T_SEQ * HDIM;
    const float* vb = v + (long)b * T_SEQ * HDIM;

    float4 q0 = *(const float4*)(qp + 0);
    float4 q1 = *(const float4*)(qp + 4);

    float s[17];
    float mx = -1e30f;
    #pragma unroll
    for (int jj = 0; jj < 17; ++jj) {
        int jr = il - 16 + jj;
        float d;
        if (jr < 0) {
            d = -1e30f;
        } else {
            const float* kr = kb + (long)jr * HDIM + p * 8;
            float4 k0 = *(const float4*)(kr + 0);
            float4 k1 = *(const float4*)(kr + 4);
            float pd = DOT4(q0, k0) + DOT4(q1, k1);
            pd += __shfl_xor(pd, 1, 64);          // 8 lanes share a row
            pd += __shfl_xor(pd, 2, 64);
            pd += __shfl_xor(pd, 4, 64);
            d = pd * 0.125f;                      // / sqrt(64)
        }
        s[jj] = d;
        mx = fmaxf(mx, d);
    }

    float denom = 0.f;
    float4 o0 = {0,0,0,0}, o1 = {0,0,0,0};
    #pragma unroll
    for (int jj = 0; jj < 17; ++jj) {
        int jr = il - 16 + jj;
        if (jr < 0) continue;
        float wgt = __expf(s[jj] - mx);
        denom += wgt;
        const float* vr = vb + (long)jr * HDIM + p * 8;
        float4 v0 = *(const float4*)(vr + 0);
        float4 v1 = *(const float4*)(vr + 4);
        o0.x += wgt * v0.x; o0.y += wgt * v0.y; o0.z += wgt * v0.z; o0.w += wgt * v0.w;
        o1.x += wgt * v1.x; o1.y += wgt * v1.y; o1.z += wgt * v1.z; o1.w += wgt * v1.w;
    }
    float inv = 1.f / denom;
    o0.x *= inv; o0.y *= inv; o0.z *= inv; o0.w *= inv;
    o1.x *= inv; o1.y *= inv; o1.z *= inv; o1.w *= inv;

    float* ob = out + ((long)b * T_SEQ + il) * HDIM + p * 8;
    *(float4*)&ob[0] = o0;
    *(float4*)&ob[4] = o1;
}

// ---------------------------------------------------------------------------
extern "C" void kernel_launch(void* const* d_in, const int* in_sizes, int n_in,
                              void* d_out, int out_size, void* d_ws, size_t ws_size,
                              hipStream_t stream) {
    const float* x  = (const float*)d_in[0];
    const float* Wq = (const float*)d_in[1];
    const float* Wk = (const float*)d_in[2];
    const float* Wv = (const float*)d_in[3];
    float* out = (float*)d_out;

    unsigned short* WT = (unsigned short*)d_ws;   // 3*64*1024*2 = 393216 B
    float* qws = (float*)((char*)d_ws + 393216);
    float* kws = qws + (long)NROWS * HDIM;
    float* vws = kws + (long)NROWS * HDIM;

    wt_kernel<<<dim3(768), dim3(256), 0, stream>>>(Wq, Wk, Wv, WT);
    qkv_kernel<<<dim3(NROWS / 32), dim3(512), 0, stream>>>(x, WT, qws, kws, vws);
    attn_kernel<<<dim3(T_SEQ / 32, NB), dim3(256), 0, stream>>>(qws, kws, vws, out);
}